// Round 3
// baseline (96.356 us; speedup 1.0000x reference)
//
#include <hip/hip_runtime.h>
#include <math.h>

// Problem constants (from reference)
#define MM 129      // mesh points per axis (odd)
#define KP 132      // padded K dim
#define NP 512      // points per batch
#define NB 4        // batches
#define NPC 16      // p-chunks (parallelism for S accumulation)
#define PCHUNK (NP / NPC)
#define FPB 16      // points per block in k_final
#define OUT_FLOATS (NB * NP * 2)
#define S_FLOAT4 ((NB * KP * KP * 2) / 4)   // 34848 float4s in S

static constexpr double D_PI  = 3.14159265358979323846;
static constexpr double D_L   = 2.0 * D_PI;
static constexpr double D_TAU = 12.0 / ((double)MM * (double)MM);
static constexpr double D_INV4TAU = 1.0 / (4.0 * D_TAU);
// scale/M^2 = 1/(8*pi^2*M^4) folded into W tables
static constexpr double D_F = 1.0 / (8.0 * D_PI * D_PI * (double)MM * (double)MM * (double)MM * (double)MM);

__device__ __forceinline__ void cmac(float2& acc, float2 a, float2 b) {
    acc.x = fmaf(a.x, b.x, fmaf(-a.y, b.y, acc.x));
    acc.y = fmaf(a.x, b.y, fmaf( a.y, b.x, acc.y));
}

// ---------------------------------------------------------------------------
// Kernel 1: per-point Gaussian sampling + DFT for k = 64..127 (Hermitian:
// A[64-j] = conj(A[64+j])); k=128 via block reduce, k=0 = conj(k=128).
// Prologue (block-granular): zero out[], build W table, zero S (S is
// accumulated by k_s1 via device-scope atomics — no fence needed, the
// dispatch boundary gives visibility; R1 showed explicit __threadfence()
// costs ~90 us in per-XCD L2 writebacks).
// 2 points/block, 1024 blocks x 128 threads.
// ---------------------------------------------------------------------------
#define PPB 2
__global__ __launch_bounds__(128) void k_dft(const float* __restrict__ x,
                                             float2* __restrict__ A,
                                             float2* __restrict__ B,
                                             const float* __restrict__ s0p,
                                             const float* __restrict__ s1p,
                                             const float* __restrict__ a0p,
                                             const float* __restrict__ a1p,
                                             float2* __restrict__ Wp,
                                             float* __restrict__ out,
                                             float2* __restrict__ S) {
    const int p0  = blockIdx.x * PPB;    // global point index (b*512+p)
    const int tid = threadIdx.x;

    // ----- fused housekeeping (cheap, block-granular) -----
    {
        const int bx = blockIdx.x;
        if (bx < 32) {                               // zero out[] (32*128 = 4096)
            out[bx * 128 + tid] = 0.f;
        } else if (bx < 100) {                       // W rows m = 0..64
            int idx = (bx - 32) * 128 + tid;
            if (idx < 65 * KP) {
                int m = idx / KP, n = idx - (idx / KP) * KP;
                float w0 = 0.f, w1 = 0.f;
                if (n < MM) {
                    float kx = (float)(m - 64), ky = (float)(n - 64);
                    float k2   = kx * kx + ky * ky;
                    float dec  = (float)(D_PI / D_TAU) * expf(k2 * (float)D_TAU);
                    float base = dec * dec * (float)(4.0 * D_PI * D_F);
                    float s0 = s0p[0], s1 = s1p[0];   // mu0 = mu1 = 1
                    w0 = a0p[0] * base / (k2 + s0 * s0);
                    w1 = a1p[0] * base / (k2 + s1 * s1);
                }
                Wp[idx] = make_float2(w0, w1);
            }
        } else if (bx < 373) {                       // zero S (atomics target)
            int idx = (bx - 100) * 128 + tid;
            if (idx < S_FLOAT4)
                ((float4*)S)[idx] = make_float4(0.f, 0.f, 0.f, 0.f);
        }
    }

    __shared__ float4 sG[MM];            // (ga_p0, gb_p0, ga_p1, gb_p1)
    __shared__ float red[2][8];

    const float inv4tau = (float)D_INV4TAU;
    const float Lf      = (float)D_L;
    for (int idx = tid; idx < MM * PPB; idx += 128) {
        int pt = idx & 1, a = idx >> 1;
        float x0 = x[(p0 + pt) * 2 + 0];
        float x1 = x[(p0 + pt) * 2 + 1];
        float u  = (float)a * (float)(D_L / MM);
        float d0 = x0 - u, d1 = x1 - u;
        float ga = __expf(-d0 * d0 * inv4tau)
                 + __expf(-(d0 - Lf) * (d0 - Lf) * inv4tau)
                 + __expf(-(d0 + Lf) * (d0 + Lf) * inv4tau);
        float gb = __expf(-d1 * d1 * inv4tau)
                 + __expf(-(d1 - Lf) * (d1 - Lf) * inv4tau)
                 + __expf(-(d1 + Lf) * (d1 + Lf) * inv4tau);
        ((float2*)&sG[a])[pt] = make_float2(ga, gb);
    }
    __syncthreads();

    const int pt = tid & 1;
    const int j  = tid >> 1;             // 0..63 -> k = 64+j, kc = j
    const int kk = 64 + j;
    const float nf = (float)(-2.0 * D_PI / MM);

    float sw, cw;
    __sincosf(nf * (float)j, &sw, &cw);  // w = exp(-2pi*i*j/M)
    const int step16 = (j * 16) % MM;
    int idx = 0;                         // (j*a) mod M at chunk start

    float Ar = 0.f, Ai = 0.f, Br = 0.f, Bi = 0.f;
    for (int c = 0; c < 128; c += 16) {
        float st, ct;
        __sincosf(nf * (float)idx, &st, &ct);          // exact resync
        float tx = ct, ty = st;
        #pragma unroll
        for (int q = 0; q < 16; ++q) {
            float2 g = ((const float2*)&sG[c + q])[pt];
            Ar = fmaf(g.x, tx, Ar); Ai = fmaf(g.x, ty, Ai);
            Br = fmaf(g.y, tx, Br); Bi = fmaf(g.y, ty, Bi);
            float nx = fmaf(tx, cw, -(ty * sw));       // t *= w
            float ny = fmaf(tx, sw,   ty * cw);
            tx = nx; ty = ny;
        }
        idx += step16; if (idx >= MM) idx -= MM;
    }
    {   // a = 128 tail (exact phase)
        float st, ct;
        __sincosf(nf * (float)idx, &st, &ct);
        float2 g = ((const float2*)&sG[128])[pt];
        Ar = fmaf(g.x, ct, Ar); Ai = fmaf(g.x, st, Ai);
        Br = fmaf(g.y, ct, Br); Bi = fmaf(g.y, st, Bi);
    }

    {
        const size_t base = (size_t)(p0 + pt) * KP;
        A[base + kk] = make_float2(Ar, Ai);
        B[base + kk] = make_float2(Br, Bi);
        if (j > 0) {                                    // Hermitian mirror
            A[base + 64 - j] = make_float2(Ar, -Ai);
            B[base + 64 - j] = make_float2(Br, -Bi);
        }
    }

    // ----- k = 128 (kc=64): reduce over a across the block; k=0 = conj -----
    const int lane = tid & 63, wv = tid >> 6;
    float2 t1, t128;
    {   // t1 = exp(-2pi*i*64*a/M) at a = tid; exact integer phase reduction
        int ph = (64 * tid) % MM;
        __sincosf(nf * (float)ph, &t1.y, &t1.x);
        __sincosf(nf * 65.f, &t128.y, &t128.x);   // (64*128) % 129 = 65
    }
    float4 gt   = sG[tid];
    float4 g128 = sG[128];
    #pragma unroll
    for (int p = 0; p < PPB; ++p) {
        float ga = p ? gt.z : gt.x;
        float gb = p ? gt.w : gt.y;
        float ar = ga * t1.x, ai = ga * t1.y;
        float br = gb * t1.x, bi = gb * t1.y;
        if (tid == 0) {   // a = 128 term
            float ga8 = p ? g128.z : g128.x;
            float gb8 = p ? g128.w : g128.y;
            ar = fmaf(ga8, t128.x, ar); ai = fmaf(ga8, t128.y, ai);
            br = fmaf(gb8, t128.x, br); bi = fmaf(gb8, t128.y, bi);
        }
        #pragma unroll
        for (int o = 32; o > 0; o >>= 1) {
            ar += __shfl_down(ar, o, 64); ai += __shfl_down(ai, o, 64);
            br += __shfl_down(br, o, 64); bi += __shfl_down(bi, o, 64);
        }
        if (lane == 0) {
            red[wv][p * 4 + 0] = ar; red[wv][p * 4 + 1] = ai;
            red[wv][p * 4 + 2] = br; red[wv][p * 4 + 3] = bi;
        }
    }
    __syncthreads();
    if (tid < 4) {
        int p = tid >> 1, isB = tid & 1;
        float re = red[0][p * 4 + isB * 2 + 0] + red[1][p * 4 + isB * 2 + 0];
        float im = red[0][p * 4 + isB * 2 + 1] + red[1][p * 4 + isB * 2 + 1];
        float2* dst = isB ? B : A;
        const size_t base = (size_t)(p0 + p) * KP;
        dst[base + 128] = make_float2(re, im);
        dst[base + 0]   = make_float2(re, -im);
    }
}

// ---------------------------------------------------------------------------
// Kernel 2: S accumulation via device-scope atomics (replaces P + k_s2).
// S[b][m][n] += sum_{p in chunk pc} A[b,p,m]*B[b,p,n]
// atomicAdd(float) on global is device-scope by default (cross-XCD safe);
// no fences. 16-way contention per address, spread over kernel lifetime.
// Grid: (17 m-tiles, 16 p-chunks, 4 batches) = 1088 blocks, 128 threads.
// ---------------------------------------------------------------------------
__global__ __launch_bounds__(128) void k_s1(const float2* __restrict__ A,
                                            const float2* __restrict__ B,
                                            float2* __restrict__ S) {
    const int b   = blockIdx.z;
    const int pc  = blockIdx.y;
    const int p0  = pc * PCHUNK;
    const int m0  = blockIdx.x * 4;       // 0..64
    const int tid = threadIdx.x;

    const float2* __restrict__ Ab = A + (size_t)b * NP * KP;
    const float2* __restrict__ Bb = B + (size_t)b * NP * KP;

    float2 acc[4];
    #pragma unroll
    for (int i = 0; i < 4; ++i) acc[i] = make_float2(0.f, 0.f);
    float2 acc2 = make_float2(0.f, 0.f);   // S[m0+lane][128], lanes 0..3

    float2 v[4], am[4][4], as[4], bu[4];
    #pragma unroll
    for (int i = 0; i < 4; ++i) {
        const size_t r = (size_t)(p0 + i) * KP;
        v[i]  = Bb[r + tid];
        bu[i] = Bb[r + 128];                 // wave-uniform
        as[i] = Ab[r + m0 + (tid & 3)];      // per-lane A for the n=128 path
        #pragma unroll
        for (int j = 0; j < 4; ++j) am[i][j] = Ab[r + m0 + j];   // wave-uniform
    }

    for (int pg = 0; pg < PCHUNK; pg += 4) {
        float2 nv[4], nam[4][4], nas[4], nbu[4];
        const bool more = (pg + 4 < PCHUNK);
        if (more) {
            #pragma unroll
            for (int i = 0; i < 4; ++i) {
                const size_t r = (size_t)(p0 + pg + 4 + i) * KP;
                nv[i]  = Bb[r + tid];
                nbu[i] = Bb[r + 128];
                nas[i] = Ab[r + m0 + (tid & 3)];
                #pragma unroll
                for (int j = 0; j < 4; ++j) nam[i][j] = Ab[r + m0 + j];
            }
        }
        #pragma unroll
        for (int i = 0; i < 4; ++i) {
            cmac(acc[0], am[i][0], v[i]);
            cmac(acc[1], am[i][1], v[i]);
            cmac(acc[2], am[i][2], v[i]);
            cmac(acc[3], am[i][3], v[i]);
        }
        if (tid < 4) {
            #pragma unroll
            for (int i = 0; i < 4; ++i) cmac(acc2, as[i], bu[i]);
        }
        if (more) {
            #pragma unroll
            for (int i = 0; i < 4; ++i) {
                v[i] = nv[i]; bu[i] = nbu[i]; as[i] = nas[i];
                #pragma unroll
                for (int j = 0; j < 4; ++j) am[i][j] = nam[i][j];
            }
        }
    }

    float* Sb = (float*)(S + (size_t)b * KP * KP);
    #pragma unroll
    for (int i = 0; i < 4; ++i) {
        float* dst = Sb + 2 * ((size_t)(m0 + i) * KP + tid);
        atomicAdd(dst + 0, acc[i].x);
        atomicAdd(dst + 1, acc[i].y);
    }
    if (tid < 4) {
        float* dst = Sb + 2 * ((size_t)(m0 + tid) * KP + 128);
        atomicAdd(dst + 0, acc2.x);
        atomicAdd(dst + 1, acc2.y);
    }
}

// ---------------------------------------------------------------------------
// Kernel 3: per point p (16 per block), both channels. Mirror symmetry:
//   full sum = 2*sum_{m<64, all n} + 2*sum_{m=64, n<64} + (m=64,n=64).
// Reduction tail via LDS transpose (bank-conflict-free, 33-stride).
// Grid: (32 point-groups, 8 m-chunks of 8 rows, 4 batches) = 1024 blocks.
// ---------------------------------------------------------------------------
__global__ __launch_bounds__(128) void k_final(const float2* __restrict__ A,
                                               const float2* __restrict__ B,
                                               const float2* __restrict__ S,
                                               const float2* __restrict__ Wp,
                                               float* __restrict__ out) {
    const int b      = blockIdx.z;
    const int mc     = blockIdx.y;
    const int mstart = mc * 8;           // rows mstart..mstart+7 (<= 63)
    const int p0     = blockIdx.x * FPB;
    const int tid    = threadIdx.x;

    __shared__ float2 sA[FPB][65];       // k = 0..64 (only m<=64 read)
    __shared__ float2 sB[FPB][KP];       // k = 0..128 used; aliased as part[] later
    __shared__ float segs[4][32];
    for (int idx = tid; idx < FPB * 65; idx += 128) {
        int pi = idx / 65, k = idx - pi * 65;
        sA[pi][k] = A[(size_t)(b * NP + p0 + pi) * KP + k];
    }
    for (int idx = tid; idx < FPB * 129; idx += 128) {
        int pi = idx / 129, k = idx - pi * 129;
        sB[pi][k] = B[(size_t)(b * NP + p0 + pi) * KP + k];
    }
    __syncthreads();

    float2 bb[FPB];
    #pragma unroll
    for (int pi = 0; pi < FPB; ++pi) bb[pi] = sB[pi][tid];

    float e0[FPB], e1[FPB];
    #pragma unroll
    for (int i = 0; i < FPB; ++i) { e0[i] = 0.f; e1[i] = 0.f; }

    const float2* __restrict__ Sb = S + (size_t)b * KP * KP;
    float2 s = Sb[(size_t)mstart * KP + tid];
    float2 w = Wp[(size_t)mstart * KP + tid];
    #pragma unroll
    for (int mi = 0; mi < 8; ++mi) {
        const int m = mstart + mi;
        float2 sn = s, wn = w;
        if (mi < 7) {
            sn = Sb[(size_t)(m + 1) * KP + tid];
            wn = Wp[(size_t)(m + 1) * KP + tid];
        }
        #pragma unroll
        for (int pi = 0; pi < FPB; ++pi) {
            float2 a  = sA[pi][m];            // broadcast
            float2 bv = bb[pi];
            float abr = a.x * bv.x - a.y * bv.y;
            float abi = a.x * bv.y + a.y * bv.x;
            float d   = fmaf(s.x, abr, s.y * abi) - fmaf(abr, abr, abi * abi);
            e0[pi] = fmaf(w.x, d, e0[pi]);
            e1[pi] = fmaf(w.y, d, e1[pi]);
        }
        s = sn; w = wn;
    }
    // n = 128 column for this chunk's rows (all m <= 63, weight 2 via fold)
    if (tid < 8) {
        const int m = mstart + tid;
        float2 s8 = Sb[(size_t)m * KP + 128];
        float2 w8 = Wp[(size_t)m * KP + 128];
        #pragma unroll
        for (int pi = 0; pi < FPB; ++pi) {
            float2 a  = sA[pi][m];
            float2 bv = sB[pi][128];
            float abr = a.x * bv.x - a.y * bv.y;
            float abi = a.x * bv.y + a.y * bv.x;
            float d   = fmaf(s8.x, abr, s8.y * abi) - fmaf(abr, abr, abi * abi);
            e0[pi] = fmaf(w8.x, d, e0[pi]);
            e1[pi] = fmaf(w8.y, d, e1[pi]);
        }
    }
    // fold the mirror weight (x2) for all m < 64 contributions
    #pragma unroll
    for (int i = 0; i < FPB; ++i) { e0[i] *= 2.f; e1[i] *= 2.f; }

    // mc==7: the self-mirror row m=64: n<64 weight 2, n=64 weight 1, n>64 none
    if (mc == 7) {
        float wt = (tid < 64) ? 2.f : ((tid == 64) ? 1.f : 0.f);
        float2 s64 = Sb[(size_t)64 * KP + tid];
        float2 w64 = Wp[(size_t)64 * KP + tid];
        w64.x *= wt; w64.y *= wt;
        #pragma unroll
        for (int pi = 0; pi < FPB; ++pi) {
            float2 a  = sA[pi][64];
            float2 bv = bb[pi];
            float abr = a.x * bv.x - a.y * bv.y;
            float abi = a.x * bv.y + a.y * bv.x;
            float d   = fmaf(s64.x, abr, s64.y * abi) - fmaf(abr, abr, abi * abi);
            e0[pi] = fmaf(w64.x, d, e0[pi]);
            e1[pi] = fmaf(w64.y, d, e1[pi]);
        }
    }

    // ----- LDS-transpose reduce: 128 threads x 32 partials -> 32 sums -----
    __syncthreads();                       // done reading sB; alias it
    float* part = (float*)&sB[0][0];       // [128][33] floats = 16896 B (exact fit)
    #pragma unroll
    for (int pi = 0; pi < FPB; ++pi) {
        part[tid * 33 + 2 * pi + 0] = e0[pi];   // bank = (tid + q) % 32: conflict-free
        part[tid * 33 + 2 * pi + 1] = e1[pi];
    }
    __syncthreads();
    {
        const int q = tid & 31, seg = tid >> 5;    // 4 segments x 32 rows
        float acc = 0.f;
        #pragma unroll
        for (int i = 0; i < 32; ++i)
            acc += part[(seg * 32 + i) * 33 + q];  // 2-way bank alias = free
        segs[seg][q] = acc;
    }
    __syncthreads();
    if (tid < 32) {
        float r = segs[0][tid] + segs[1][tid] + segs[2][tid] + segs[3][tid];
        int pi = tid >> 1, c = tid & 1;
        atomicAdd(&out[((size_t)(b * NP + p0 + pi)) * 2 + c], r);
    }
}

// ---------------------------------------------------------------------------
extern "C" void kernel_launch(void* const* d_in, const int* in_sizes, int n_in,
                              void* d_out, int out_size, void* d_ws, size_t ws_size,
                              hipStream_t stream) {
    const float* x      = (const float*)d_in[0];
    const float* shift0 = (const float*)d_in[1];
    const float* shift1 = (const float*)d_in[2];
    const float* amp0   = (const float*)d_in[3];
    const float* amp1   = (const float*)d_in[4];
    float* out = (float*)d_out;

    // workspace layout (float2-aligned)
    float2* A  = (float2*)d_ws;                 // [NB][NP][KP]
    float2* Bv = A + (size_t)NB * NP * KP;      // [NB][NP][KP]
    float2* S  = Bv + (size_t)NB * NP * KP;     // [NB][KP][KP] (atomic-accumulated)
    float2* Wp = S + (size_t)NB * KP * KP;      // [65*KP] packed (w0,w1)

    k_dft<<<(NB * NP) / PPB, 128, 0, stream>>>(x, A, Bv, shift0, shift1,
                                               amp0, amp1, Wp, out, S);
    k_s1<<<dim3(17, NPC, NB), 128, 0, stream>>>(A, Bv, S);
    k_final<<<dim3(NP / FPB, 8, NB), 128, 0, stream>>>(A, Bv, S, Wp, out);
}

// Round 4
// 95.178 us; speedup vs baseline: 1.0124x; 1.0124x over previous
//
#include <hip/hip_runtime.h>
#include <math.h>

// Problem constants (from reference)
#define MM 129      // mesh points per axis (odd)
#define KP 132      // padded K dim
#define NP 512      // points per batch
#define NB 4        // batches
#define NPC 16      // p-chunks for the two-stage S reduction
#define PCHUNK (NP / NPC)
#define FPB 16      // points per block in k_final
#define OUT_FLOATS (NB * NP * 2)

static constexpr double D_PI  = 3.14159265358979323846;
static constexpr double D_L   = 2.0 * D_PI;
static constexpr double D_TAU = 12.0 / ((double)MM * (double)MM);
static constexpr double D_INV4TAU = 1.0 / (4.0 * D_TAU);
// scale/M^2 = 1/(8*pi^2*M^4) folded into W tables
static constexpr double D_F = 1.0 / (8.0 * D_PI * D_PI * (double)MM * (double)MM * (double)MM * (double)MM);

__device__ __forceinline__ void cmac(float2& acc, float2 a, float2 b) {
    acc.x = fmaf(a.x, b.x, fmaf(-a.y, b.y, acc.x));
    acc.y = fmaf(a.x, b.y, fmaf( a.y, b.x, acc.y));
}

// ---------------------------------------------------------------------------
// Kernel 1: per-point Gaussian sampling + DFT for k = 64..127 (Hermitian:
// A[64-j] = conj(A[64+j])); k=128 via block reduce, k=0 = conj(k=128).
// Prologue (blocks 0..99): zero out[], build W table.
// Session history: R1's fused last-block-wins reduction cost ~90 us in
// device-scope fences (per-XCD L2 writebacks); R3's atomic-S accumulation
// was neutral-to-worse than the P+k_s2 two-stage reduction. This is the
// best-measured structure (R2: 95.47 us).
// 2 points/block, 1024 blocks x 128 threads.
// ---------------------------------------------------------------------------
#define PPB 2
__global__ __launch_bounds__(128) void k_dft(const float* __restrict__ x,
                                             float2* __restrict__ A,
                                             float2* __restrict__ B,
                                             const float* __restrict__ s0p,
                                             const float* __restrict__ s1p,
                                             const float* __restrict__ a0p,
                                             const float* __restrict__ a1p,
                                             float2* __restrict__ Wp,
                                             float* __restrict__ out) {
    const int p0  = blockIdx.x * PPB;    // global point index (b*512+p)
    const int tid = threadIdx.x;

    // ----- fused housekeeping (cheap, block-granular) -----
    {
        const int bx = blockIdx.x;
        if (bx < 32) {                               // zero out[] (32*128 = 4096)
            out[bx * 128 + tid] = 0.f;
        } else if (bx < 100) {                       // W rows m = 0..64
            int idx = (bx - 32) * 128 + tid;
            if (idx < 65 * KP) {
                int m = idx / KP, n = idx - (idx / KP) * KP;
                float w0 = 0.f, w1 = 0.f;
                if (n < MM) {
                    float kx = (float)(m - 64), ky = (float)(n - 64);
                    float k2   = kx * kx + ky * ky;
                    float dec  = (float)(D_PI / D_TAU) * expf(k2 * (float)D_TAU);
                    float base = dec * dec * (float)(4.0 * D_PI * D_F);
                    float s0 = s0p[0], s1 = s1p[0];   // mu0 = mu1 = 1
                    w0 = a0p[0] * base / (k2 + s0 * s0);
                    w1 = a1p[0] * base / (k2 + s1 * s1);
                }
                Wp[idx] = make_float2(w0, w1);
            }
        }
    }

    __shared__ float4 sG[MM];            // (ga_p0, gb_p0, ga_p1, gb_p1)
    __shared__ float red[2][8];

    const float inv4tau = (float)D_INV4TAU;
    const float Lf      = (float)D_L;
    for (int idx = tid; idx < MM * PPB; idx += 128) {
        int pt = idx & 1, a = idx >> 1;
        float x0 = x[(p0 + pt) * 2 + 0];
        float x1 = x[(p0 + pt) * 2 + 1];
        float u  = (float)a * (float)(D_L / MM);
        float d0 = x0 - u, d1 = x1 - u;
        float ga = __expf(-d0 * d0 * inv4tau)
                 + __expf(-(d0 - Lf) * (d0 - Lf) * inv4tau)
                 + __expf(-(d0 + Lf) * (d0 + Lf) * inv4tau);
        float gb = __expf(-d1 * d1 * inv4tau)
                 + __expf(-(d1 - Lf) * (d1 - Lf) * inv4tau)
                 + __expf(-(d1 + Lf) * (d1 + Lf) * inv4tau);
        ((float2*)&sG[a])[pt] = make_float2(ga, gb);
    }
    __syncthreads();

    const int pt = tid & 1;
    const int j  = tid >> 1;             // 0..63 -> k = 64+j, kc = j
    const int kk = 64 + j;
    const float nf = (float)(-2.0 * D_PI / MM);

    float sw, cw;
    __sincosf(nf * (float)j, &sw, &cw);  // w = exp(-2pi*i*j/M)
    const int step16 = (j * 16) % MM;
    int idx = 0;                         // (j*a) mod M at chunk start

    float Ar = 0.f, Ai = 0.f, Br = 0.f, Bi = 0.f;
    for (int c = 0; c < 128; c += 16) {
        float st, ct;
        __sincosf(nf * (float)idx, &st, &ct);          // exact resync
        float tx = ct, ty = st;
        #pragma unroll
        for (int q = 0; q < 16; ++q) {
            float2 g = ((const float2*)&sG[c + q])[pt];
            Ar = fmaf(g.x, tx, Ar); Ai = fmaf(g.x, ty, Ai);
            Br = fmaf(g.y, tx, Br); Bi = fmaf(g.y, ty, Bi);
            float nx = fmaf(tx, cw, -(ty * sw));       // t *= w
            float ny = fmaf(tx, sw,   ty * cw);
            tx = nx; ty = ny;
        }
        idx += step16; if (idx >= MM) idx -= MM;
    }
    {   // a = 128 tail (exact phase)
        float st, ct;
        __sincosf(nf * (float)idx, &st, &ct);
        float2 g = ((const float2*)&sG[128])[pt];
        Ar = fmaf(g.x, ct, Ar); Ai = fmaf(g.x, st, Ai);
        Br = fmaf(g.y, ct, Br); Bi = fmaf(g.y, st, Bi);
    }

    {
        const size_t base = (size_t)(p0 + pt) * KP;
        A[base + kk] = make_float2(Ar, Ai);
        B[base + kk] = make_float2(Br, Bi);
        if (j > 0) {                                    // Hermitian mirror
            A[base + 64 - j] = make_float2(Ar, -Ai);
            B[base + 64 - j] = make_float2(Br, -Bi);
        }
    }

    // ----- k = 128 (kc=64): reduce over a across the block; k=0 = conj -----
    const int lane = tid & 63, wv = tid >> 6;
    float2 t1, t128;
    {   // t1 = exp(-2pi*i*64*a/M) at a = tid; exact integer phase reduction
        int ph = (64 * tid) % MM;
        __sincosf(nf * (float)ph, &t1.y, &t1.x);
        __sincosf(nf * 65.f, &t128.y, &t128.x);   // (64*128) % 129 = 65
    }
    float4 gt   = sG[tid];
    float4 g128 = sG[128];
    #pragma unroll
    for (int p = 0; p < PPB; ++p) {
        float ga = p ? gt.z : gt.x;
        float gb = p ? gt.w : gt.y;
        float ar = ga * t1.x, ai = ga * t1.y;
        float br = gb * t1.x, bi = gb * t1.y;
        if (tid == 0) {   // a = 128 term
            float ga8 = p ? g128.z : g128.x;
            float gb8 = p ? g128.w : g128.y;
            ar = fmaf(ga8, t128.x, ar); ai = fmaf(ga8, t128.y, ai);
            br = fmaf(gb8, t128.x, br); bi = fmaf(gb8, t128.y, bi);
        }
        #pragma unroll
        for (int o = 32; o > 0; o >>= 1) {
            ar += __shfl_down(ar, o, 64); ai += __shfl_down(ai, o, 64);
            br += __shfl_down(br, o, 64); bi += __shfl_down(bi, o, 64);
        }
        if (lane == 0) {
            red[wv][p * 4 + 0] = ar; red[wv][p * 4 + 1] = ai;
            red[wv][p * 4 + 2] = br; red[wv][p * 4 + 3] = bi;
        }
    }
    __syncthreads();
    if (tid < 4) {
        int p = tid >> 1, isB = tid & 1;
        float re = red[0][p * 4 + isB * 2 + 0] + red[1][p * 4 + isB * 2 + 0];
        float im = red[0][p * 4 + isB * 2 + 1] + red[1][p * 4 + isB * 2 + 1];
        float2* dst = isB ? B : A;
        const size_t base = (size_t)(p0 + p) * KP;
        dst[base + 128] = make_float2(re, im);
        dst[base + 0]   = make_float2(re, -im);
    }
}

// ---------------------------------------------------------------------------
// Kernel 2a: stage-1 of S: partial outer products, NO atomics, NO fences.
// P[b][pc][m(0..67)][n] = sum_{p in chunk pc} A[b,p,m]*B[b,p,n]
// Grid: (17 m-tiles, 16 p-chunks, 4 batches) = 1088 blocks, 128 threads.
// ---------------------------------------------------------------------------
__global__ __launch_bounds__(128) void k_s1(const float2* __restrict__ A,
                                            const float2* __restrict__ B,
                                            float2* __restrict__ P) {
    const int b   = blockIdx.z;
    const int pc  = blockIdx.y;
    const int p0  = pc * PCHUNK;
    const int m0  = blockIdx.x * 4;       // 0..64
    const int tid = threadIdx.x;

    const float2* __restrict__ Ab = A + (size_t)b * NP * KP;
    const float2* __restrict__ Bb = B + (size_t)b * NP * KP;

    float2 acc[4];
    #pragma unroll
    for (int i = 0; i < 4; ++i) acc[i] = make_float2(0.f, 0.f);
    float2 acc2 = make_float2(0.f, 0.f);   // P[m0+lane][128], lanes 0..3

    float2 v[4], am[4][4], as[4], bu[4];
    #pragma unroll
    for (int i = 0; i < 4; ++i) {
        const size_t r = (size_t)(p0 + i) * KP;
        v[i]  = Bb[r + tid];
        bu[i] = Bb[r + 128];                 // wave-uniform
        as[i] = Ab[r + m0 + (tid & 3)];      // per-lane A for the n=128 path
        #pragma unroll
        for (int j = 0; j < 4; ++j) am[i][j] = Ab[r + m0 + j];   // wave-uniform
    }

    for (int pg = 0; pg < PCHUNK; pg += 4) {
        float2 nv[4], nam[4][4], nas[4], nbu[4];
        const bool more = (pg + 4 < PCHUNK);
        if (more) {
            #pragma unroll
            for (int i = 0; i < 4; ++i) {
                const size_t r = (size_t)(p0 + pg + 4 + i) * KP;
                nv[i]  = Bb[r + tid];
                nbu[i] = Bb[r + 128];
                nas[i] = Ab[r + m0 + (tid & 3)];
                #pragma unroll
                for (int j = 0; j < 4; ++j) nam[i][j] = Ab[r + m0 + j];
            }
        }
        #pragma unroll
        for (int i = 0; i < 4; ++i) {
            cmac(acc[0], am[i][0], v[i]);
            cmac(acc[1], am[i][1], v[i]);
            cmac(acc[2], am[i][2], v[i]);
            cmac(acc[3], am[i][3], v[i]);
        }
        if (tid < 4) {
            #pragma unroll
            for (int i = 0; i < 4; ++i) cmac(acc2, as[i], bu[i]);
        }
        if (more) {
            #pragma unroll
            for (int i = 0; i < 4; ++i) {
                v[i] = nv[i]; bu[i] = nbu[i]; as[i] = nas[i];
                #pragma unroll
                for (int j = 0; j < 4; ++j) am[i][j] = nam[i][j];
            }
        }
    }

    float2* Pb = P + ((size_t)(b * NPC + pc) * 68) * KP;
    #pragma unroll
    for (int i = 0; i < 4; ++i)
        Pb[(size_t)(m0 + i) * KP + tid] = acc[i];      // coalesced store
    if (tid < 4)
        Pb[(size_t)(m0 + tid) * KP + 128] = acc2;
}

// ---------------------------------------------------------------------------
// Kernel 2b: reduction-only: S[b][m][n] = sum_pc P[b][pc][m][n].
// (W build + out zeroing live in k_dft's prologue.) The 16 P-loads per
// thread are independent -> issued concurrently, one latency exposure.
// ---------------------------------------------------------------------------
__global__ __launch_bounds__(256) void k_s2(const float2* __restrict__ P,
                                            float2* __restrict__ S) {
    const int idx = blockIdx.x * 256 + threadIdx.x;
    if (idx >= NB * 65 * KP) return;
    const int b   = idx / (65 * KP);
    const int rem = idx - b * (65 * KP);
    const int m   = rem / KP;
    const int n   = rem - m * KP;
    if (n > 128) return;                  // cols 129..131 never written/read
    const float2* __restrict__ Pb =
        P + ((size_t)b * NPC * 68) * KP + (size_t)m * KP + n;
    float re = 0.f, im = 0.f;
    #pragma unroll
    for (int pc = 0; pc < NPC; ++pc) {
        float2 vv = Pb[(size_t)pc * 68 * KP];
        re += vv.x; im += vv.y;
    }
    S[(size_t)b * KP * KP + (size_t)m * KP + n] = make_float2(re, im);
}

// ---------------------------------------------------------------------------
// Kernel 3: per point p (16 per block), both channels. Mirror symmetry:
//   full sum = 2*sum_{m<64, all n} + 2*sum_{m=64, n<64} + (m=64,n=64).
// 16 pts/block halves S/W row re-reads vs the 8-pt version; the reduction
// tail uses an LDS transpose (bank-conflict-free via 33-stride) instead of
// shuffle trees.
// Grid: (32 point-groups, 8 m-chunks of 8 rows, 4 batches) = 1024 blocks.
// ---------------------------------------------------------------------------
__global__ __launch_bounds__(128) void k_final(const float2* __restrict__ A,
                                               const float2* __restrict__ B,
                                               const float2* __restrict__ S,
                                               const float2* __restrict__ Wp,
                                               float* __restrict__ out) {
    const int b      = blockIdx.z;
    const int mc     = blockIdx.y;
    const int mstart = mc * 8;           // rows mstart..mstart+7 (<= 63)
    const int p0     = blockIdx.x * FPB;
    const int tid    = threadIdx.x;

    __shared__ float2 sA[FPB][65];       // k = 0..64 (only m<=64 read)
    __shared__ float2 sB[FPB][KP];       // k = 0..128 used; aliased as part[] later
    __shared__ float segs[4][32];
    for (int idx = tid; idx < FPB * 65; idx += 128) {
        int pi = idx / 65, k = idx - pi * 65;
        sA[pi][k] = A[(size_t)(b * NP + p0 + pi) * KP + k];
    }
    for (int idx = tid; idx < FPB * 129; idx += 128) {
        int pi = idx / 129, k = idx - pi * 129;
        sB[pi][k] = B[(size_t)(b * NP + p0 + pi) * KP + k];
    }
    __syncthreads();

    float2 bb[FPB];
    #pragma unroll
    for (int pi = 0; pi < FPB; ++pi) bb[pi] = sB[pi][tid];

    float e0[FPB], e1[FPB];
    #pragma unroll
    for (int i = 0; i < FPB; ++i) { e0[i] = 0.f; e1[i] = 0.f; }

    const float2* __restrict__ Sb = S + (size_t)b * KP * KP;
    float2 s = Sb[(size_t)mstart * KP + tid];
    float2 w = Wp[(size_t)mstart * KP + tid];
    #pragma unroll
    for (int mi = 0; mi < 8; ++mi) {
        const int m = mstart + mi;
        float2 sn = s, wn = w;
        if (mi < 7) {
            sn = Sb[(size_t)(m + 1) * KP + tid];
            wn = Wp[(size_t)(m + 1) * KP + tid];
        }
        #pragma unroll
        for (int pi = 0; pi < FPB; ++pi) {
            float2 a  = sA[pi][m];            // broadcast
            float2 bv = bb[pi];
            float abr = a.x * bv.x - a.y * bv.y;
            float abi = a.x * bv.y + a.y * bv.x;
            float d   = fmaf(s.x, abr, s.y * abi) - fmaf(abr, abr, abi * abi);
            e0[pi] = fmaf(w.x, d, e0[pi]);
            e1[pi] = fmaf(w.y, d, e1[pi]);
        }
        s = sn; w = wn;
    }
    // n = 128 column for this chunk's rows (all m <= 63, weight 2 via fold)
    if (tid < 8) {
        const int m = mstart + tid;
        float2 s8 = Sb[(size_t)m * KP + 128];
        float2 w8 = Wp[(size_t)m * KP + 128];
        #pragma unroll
        for (int pi = 0; pi < FPB; ++pi) {
            float2 a  = sA[pi][m];
            float2 bv = sB[pi][128];
            float abr = a.x * bv.x - a.y * bv.y;
            float abi = a.x * bv.y + a.y * bv.x;
            float d   = fmaf(s8.x, abr, s8.y * abi) - fmaf(abr, abr, abi * abi);
            e0[pi] = fmaf(w8.x, d, e0[pi]);
            e1[pi] = fmaf(w8.y, d, e1[pi]);
        }
    }
    // fold the mirror weight (x2) for all m < 64 contributions
    #pragma unroll
    for (int i = 0; i < FPB; ++i) { e0[i] *= 2.f; e1[i] *= 2.f; }

    // mc==7: the self-mirror row m=64: n<64 weight 2, n=64 weight 1, n>64 none
    if (mc == 7) {
        float wt = (tid < 64) ? 2.f : ((tid == 64) ? 1.f : 0.f);
        float2 s64 = Sb[(size_t)64 * KP + tid];
        float2 w64 = Wp[(size_t)64 * KP + tid];
        w64.x *= wt; w64.y *= wt;
        #pragma unroll
        for (int pi = 0; pi < FPB; ++pi) {
            float2 a  = sA[pi][64];
            float2 bv = bb[pi];
            float abr = a.x * bv.x - a.y * bv.y;
            float abi = a.x * bv.y + a.y * bv.x;
            float d   = fmaf(s64.x, abr, s64.y * abi) - fmaf(abr, abr, abi * abi);
            e0[pi] = fmaf(w64.x, d, e0[pi]);
            e1[pi] = fmaf(w64.y, d, e1[pi]);
        }
    }

    // ----- LDS-transpose reduce: 128 threads x 32 partials -> 32 sums -----
    __syncthreads();                       // done reading sB; alias it
    float* part = (float*)&sB[0][0];       // [128][33] floats = 16896 B (exact fit)
    #pragma unroll
    for (int pi = 0; pi < FPB; ++pi) {
        part[tid * 33 + 2 * pi + 0] = e0[pi];   // bank = (tid + q) % 32: conflict-free
        part[tid * 33 + 2 * pi + 1] = e1[pi];
    }
    __syncthreads();
    {
        const int q = tid & 31, seg = tid >> 5;    // 4 segments x 32 rows
        float acc = 0.f;
        #pragma unroll
        for (int i = 0; i < 32; ++i)
            acc += part[(seg * 32 + i) * 33 + q];  // 2-way bank alias = free
        segs[seg][q] = acc;
    }
    __syncthreads();
    if (tid < 32) {
        float r = segs[0][tid] + segs[1][tid] + segs[2][tid] + segs[3][tid];
        int pi = tid >> 1, c = tid & 1;
        atomicAdd(&out[((size_t)(b * NP + p0 + pi)) * 2 + c], r);
    }
}

// ---------------------------------------------------------------------------
extern "C" void kernel_launch(void* const* d_in, const int* in_sizes, int n_in,
                              void* d_out, int out_size, void* d_ws, size_t ws_size,
                              hipStream_t stream) {
    const float* x      = (const float*)d_in[0];
    const float* shift0 = (const float*)d_in[1];
    const float* shift1 = (const float*)d_in[2];
    const float* amp0   = (const float*)d_in[3];
    const float* amp1   = (const float*)d_in[4];
    float* out = (float*)d_out;

    // workspace layout (float2-aligned)
    float2* A  = (float2*)d_ws;                 // [NB][NP][KP]
    float2* Bv = A + (size_t)NB * NP * KP;      // [NB][NP][KP]
    float2* S  = Bv + (size_t)NB * NP * KP;     // [NB][KP][KP]
    float2* Wp = S + (size_t)NB * KP * KP;      // [65*KP] packed (w0,w1)
    float2* P  = Wp + (size_t)65 * KP;          // [NB*NPC][68][KP] partials (~4.6 MB)

    k_dft<<<(NB * NP) / PPB, 128, 0, stream>>>(x, A, Bv, shift0, shift1,
                                               amp0, amp1, Wp, out);
    k_s1<<<dim3(17, NPC, NB), 128, 0, stream>>>(A, Bv, P);
    k_s2<<<(NB * 65 * KP + 255) / 256, 256, 0, stream>>>(P, S);
    k_final<<<dim3(NP / FPB, 8, NB), 128, 0, stream>>>(A, Bv, S, Wp, out);
}